// Round 8
// baseline (277.616 us; speedup 1.0000x reference)
//
#include <hip/hip_runtime.h>
#include <math.h>

constexpr int NN = 200000;
constexpr int EE = 6400000;
constexpr int NB = (NN + 255) / 256;        // 782 blocks of 256 (node-parallel kernels)
constexpr int U_ = 200000, T_ = 20000, C_ = 5000, G_ = 10000;

constexpr int BSH2  = 9;                    // 512 nodes per bucket
constexpr int BUCKN = 1 << BSH2;
constexpr int NBUCK = (NN + BUCKN - 1) / BUCKN;   // 391 (last bucket: 320 nodes)
constexpr int CAP   = 18432;                // padded bucket capacity (mean 16368, ~16 sigma)
constexpr int CHUNK  = 4096;                // edges per binning block (31KB LDS -> 5 blocks/CU)
constexpr int NCHUNK = (EE + CHUNK - 1) / CHUNK;  // 1563

__device__ __forceinline__ int clampi(int v, int lo, int hi){ return v < lo ? lo : (v > hi ? hi : v); }
__device__ __forceinline__ float reluf(float v){ return v > 0.f ? v : 0.f; }

// ---- init padded-bucket cursors -----------------------------------------

__global__ void k_init(int* __restrict__ binCur){
  int t = blockIdx.x * 256 + threadIdx.x;
  if (t < NBUCK) binCur[t] = t * CAP;
}

// ---- Phase A: LDS-staged binning into padded buckets ---------------------
// Packed entry: row (bits 0..17, NN < 2^18) | local_col (bits 18..26).
// Pass 3 uses a 16-bit bucket side-array instead of a binary search:
// 2 independent LDS reads per edge, no dependent-load chain.

__global__ void k_binA(const int* __restrict__ edges, int* __restrict__ binCur,
                       int* __restrict__ bin){
  __shared__ int hist[NBUCK];
  __shared__ int dlt[NBUCK];
  __shared__ int cur[NBUCK];
  __shared__ int sc[256];
  __shared__ int stage[CHUNK];
  __shared__ unsigned short stageB[CHUNK];

  int t = threadIdx.x;
  int base = blockIdx.x * CHUNK;
  int n = min(CHUNK, EE - base);

  for (int i = t; i < NBUCK; i += 256) hist[i] = 0;
  __syncthreads();
  // pass 1: LDS histogram over buckets
  for (int k = t; k < n; k += 256)
    atomicAdd(&hist[edges[EE + base + k] >> BSH2], 1);
  __syncthreads();
  // exclusive scan (thread t owns bins 2t, 2t+1)
  int b0i = 2 * t, b1i = 2 * t + 1;
  int h0 = (b0i < NBUCK) ? hist[b0i] : 0;
  int h1 = (b1i < NBUCK) ? hist[b1i] : 0;
  int tot = h0 + h1;
  sc[t] = tot; __syncthreads();
  for (int d = 1; d < 256; d <<= 1){
    int u = (t >= d) ? sc[t - d] : 0;
    __syncthreads();
    sc[t] += u;
    __syncthreads();
  }
  int excl = sc[t] - tot;
  if (b0i < NBUCK) cur[b0i] = excl;
  if (b1i < NBUCK) cur[b1i] = excl + h0;
  // reserve global space: ONE atomic per (block,bucket)
  if (b0i < NBUCK) dlt[b0i] = (h0 > 0 ? atomicAdd(&binCur[b0i], h0) : 0) - excl;
  if (b1i < NBUCK) dlt[b1i] = (h1 > 0 ? atomicAdd(&binCur[b1i], h1) : 0) - (excl + h0);
  __syncthreads();
  // pass 2: scatter packed entries + bucket id into LDS staging
  for (int k = t; k < n; k += 256){
    int c = edges[EE + base + k];
    int r = edges[base + k];
    int b = c >> BSH2;
    int p = atomicAdd(&cur[b], 1);
    stage[p]  = r | ((c & (BUCKN - 1)) << 18);
    stageB[p] = (unsigned short)b;
  }
  __syncthreads();
  // pass 3: write runs out; consecutive k -> consecutive global addr within a run
  for (int k = t; k < n; k += 256){
    int b = stageB[k];
    int addr = dlt[b] + k;
    if (addr < (b + 1) * CAP)            // overflow guard (16-sigma margin)
      bin[addr] = stage[k];
  }
}

// ---- Phase B: per-bucket CSR finalize, sorted by (local_col, row_quarter) -
// Emits off/cnt/seg/dis densely; srow within the bucket's contiguous extent.
// seg packs the 3 interior quarter boundaries (10 bits each).

__global__ __launch_bounds__(512) void k_binB2(
    const int* __restrict__ bin, const int* __restrict__ binCur,
    int* __restrict__ off, int* __restrict__ cnt, int* __restrict__ seg,
    double* __restrict__ dis, int* __restrict__ srow){
  __shared__ int hist[4 * BUCKN];   // 2048 keys: (lc<<2)|rq  -> reused as cursors
  __shared__ int sc[512];
  int t = threadIdx.x;
  int b = blockIdx.x;
  int nb = b << BSH2;
  int nloc = min(BUCKN, NN - nb);
  int s0 = b * CAP, s1 = binCur[b];

  hist[t] = 0; hist[t + 512] = 0; hist[t + 1024] = 0; hist[t + 1536] = 0;
  __syncthreads();
  for (int k = s0 + t; k < s1; k += 512){
    int w = bin[k];
    int key = ((w >> 18) << 2) | ((w & 0x3FFFF) >> 16);   // rq = row>>16 in 0..3
    atomicAdd(&hist[key], 1);
  }
  __syncthreads();
  int h0 = hist[4*t], h1 = hist[4*t+1], h2 = hist[4*t+2], h3 = hist[4*t+3];
  int tot = h0 + h1 + h2 + h3;
  sc[t] = tot; __syncthreads();
  for (int d = 1; d < 512; d <<= 1){
    int u = (t >= d) ? sc[t - d] : 0;
    __syncthreads();
    sc[t] += u;
    __syncthreads();
  }
  int base = sc[t] - tot;                    // exclusive prefix within bucket
  if (t < nloc){
    off[nb + t] = s0 + base;
    cnt[nb + t] = tot;
    seg[nb + t] = h0 | ((h0 + h1) << 10) | ((h0 + h1 + h2) << 20);
    dis[nb + t] = 1.0 / sqrt((double)(tot + 1));   // deg includes self-loop
  }
  __syncthreads();
  hist[4*t]     = base;                      // per-(lc,rq) cursors
  hist[4*t + 1] = base + h0;
  hist[4*t + 2] = base + h0 + h1;
  hist[4*t + 3] = base + h0 + h1 + h2;
  __syncthreads();
  for (int k = s0 + t; k < s1; k += 512){
    int w = bin[k];
    int key = ((w >> 18) << 2) | ((w & 0x3FFFF) >> 16);
    int p = atomicAdd(&hist[key], 1);
    srow[s0 + p] = w & 0x3FFFF;
  }
}

// ---- feature assembly + dis pre-scale -----------------------------------
// xs1[i][k] = dis[i] * x_i[k]   (8 floats/node; W0 applied AFTER aggregation)

__global__ void k_assemble(
    const int* __restrict__ features, const int* __restrict__ lmask,
    const float* __restrict__ user_emb, const float* __restrict__ known_emb,
    const float* __restrict__ mask_emb, const float* __restrict__ cat_emb,
    const float* __restrict__ topic_emb, const float* __restrict__ group_emb,
    const float* __restrict__ user_W, const float* __restrict__ user_b,
    const float* __restrict__ mask_W, const float* __restrict__ mask_b,
    const float* __restrict__ cat_W, const float* __restrict__ cat_b,
    const float* __restrict__ topic_W, const float* __restrict__ topic_b,
    const float* __restrict__ group_W, const float* __restrict__ group_b,
    const double* __restrict__ dis, float* __restrict__ xs1)
{
  __shared__ float s_userW[64], s_topicW[64], s_groupW[64], s_maskW[64];
  __shared__ float s_catW[16], s_knownE[16], s_maskE[16];
  __shared__ float s_userb[8], s_topicb[8], s_catb[8], s_groupb[8], s_maskb[8];
  int tid = threadIdx.x;
  if (tid < 64){ s_userW[tid]=user_W[tid]; s_topicW[tid]=topic_W[tid];
                 s_groupW[tid]=group_W[tid]; s_maskW[tid]=mask_W[tid]; }
  if (tid < 16){ s_catW[tid]=cat_W[tid]; s_knownE[tid]=known_emb[tid]; s_maskE[tid]=mask_emb[tid]; }
  if (tid < 8){ s_userb[tid]=user_b[tid]; s_topicb[tid]=topic_b[tid]; s_catb[tid]=cat_b[tid];
                s_groupb[tid]=group_b[tid]; s_maskb[tid]=mask_b[tid]; }
  __syncthreads();

  int i = blockIdx.x * 256 + tid;
  if (i >= NN) return;

  int idx   = features[3*i + 0];
  int known = features[3*i + 1];
  int tc    = features[3*i + 2];

  double x[8];
  #pragma unroll
  for (int k = 0; k < 8; k++) x[k] = 0.0;

  if (tc == 0){
    int id = clampi(idx, 0, U_-1);
    int kn = clampi(known, 0, 1);
    float a[8];
    #pragma unroll
    for (int d = 0; d < 8; d++) a[d] = reluf(user_emb[(size_t)id*8 + d] + s_knownE[kn*8 + d]);
    #pragma unroll
    for (int k = 0; k < 8; k++){
      double s = (double)s_userb[k];
      #pragma unroll
      for (int d = 0; d < 8; d++) s += (double)a[d] * (double)s_userW[d*8 + k];
      x[k] = s;
    }
  } else if (tc == 1){
    int id = clampi(idx, 0, T_-1);
    float a[8];
    #pragma unroll
    for (int d = 0; d < 8; d++) a[d] = reluf(topic_emb[(size_t)id*8 + d]);
    #pragma unroll
    for (int k = 0; k < 8; k++){
      double s = (double)s_topicb[k];
      #pragma unroll
      for (int d = 0; d < 8; d++) s += (double)a[d] * (double)s_topicW[d*8 + k];
      x[k] = s;
    }
  } else if (tc == 2){
    int id = clampi(idx, 0, C_-1);
    float a0 = reluf(cat_emb[(size_t)id*2 + 0]);
    float a1 = reluf(cat_emb[(size_t)id*2 + 1]);
    #pragma unroll
    for (int k = 0; k < 8; k++)
      x[k] = (double)s_catb[k] + (double)a0*(double)s_catW[k] + (double)a1*(double)s_catW[8 + k];
  } else if (tc == 4){
    int id = clampi(idx, 0, G_-1);
    float a[8];
    #pragma unroll
    for (int d = 0; d < 8; d++) a[d] = reluf(group_emb[(size_t)id*8 + d]);
    #pragma unroll
    for (int k = 0; k < 8; k++){
      double s = (double)s_groupb[k];
      #pragma unroll
      for (int d = 0; d < 8; d++) s += (double)a[d] * (double)s_groupW[d*8 + k];
      x[k] = s;
    }
  } // else: x stays 0 (tcode 3 unused)

  int m = clampi(lmask[i], 0, 1);
  float me[8];
  #pragma unroll
  for (int d = 0; d < 8; d++) me[d] = reluf(s_maskE[m*8 + d]);
  double di = dis[i];
  float xo[8];
  #pragma unroll
  for (int k = 0; k < 8; k++){
    double s = (double)s_maskb[k];
    #pragma unroll
    for (int d = 0; d < 8; d++) s += (double)me[d] * (double)s_maskW[d*8 + k];
    double mf = 1.0 / (1.0 + exp(-s));
    xo[k] = (float)(di * x[k] * mf);
  }
  float4* xp = (float4*)(xs1 + (size_t)i * 8);
  xp[0] = make_float4(xo[0], xo[1], xo[2], xo[3]);
  xp[1] = make_float4(xo[4], xo[5], xo[6], xo[7]);
}

// ---- layer 1: phased gather-aggregate, then W0 + relu + W2 dot -----------
// 2 lanes per node (lane h owns comps h*4..h*4+3). Neighbor lists are sorted
// by row-quarter; all co-resident blocks walk quarters in the same order so
// the instantaneous gather working set (~2.1 MB) stays L2-resident.

__global__ void k_agg1(const float* __restrict__ xs1, const int* __restrict__ srow,
                       const int* __restrict__ off, const int* __restrict__ cnt,
                       const int* __restrict__ seg, const double* __restrict__ dis,
                       const float* __restrict__ b0, const float* __restrict__ W0,
                       const float* __restrict__ W2, float* __restrict__ h2s)
{
  __shared__ float sW0[128], sb0[16], sW2[16];
  int tid = threadIdx.x;
  if (tid < 128) sW0[tid] = W0[tid];
  if (tid < 16){ sb0[tid] = b0[tid]; sW2[tid] = W2[tid]; }
  __syncthreads();

  int gid = blockIdx.x * 256 + tid;
  int i = gid >> 1, h = gid & 1;
  if (i >= NN) return;

  const float4* xp = (const float4*)xs1;
  float4 sv = xp[(size_t)i*2 + h];                 // self-loop
  double a0 = sv.x, a1 = sv.y, a2 = sv.z, a3 = sv.w;
  int s = off[i], c = cnt[i], sg = seg[i];
  int bnd[5];
  bnd[0] = 0;
  bnd[1] = sg & 1023;
  bnd[2] = (sg >> 10) & 1023;
  bnd[3] = (sg >> 20) & 1023;
  bnd[4] = c;
  #pragma unroll 1
  for (int p = 0; p < 4; p++){
    int j = bnd[p], je = bnd[p + 1];
    for (; j + 4 <= je; j += 4){                   // 4 gathers in flight
      int r0 = srow[s+j], r1 = srow[s+j+1], r2 = srow[s+j+2], r3 = srow[s+j+3];
      float4 v0 = xp[(size_t)r0*2 + h], v1 = xp[(size_t)r1*2 + h],
             v2 = xp[(size_t)r2*2 + h], v3 = xp[(size_t)r3*2 + h];
      a0 += v0.x; a1 += v0.y; a2 += v0.z; a3 += v0.w;
      a0 += v1.x; a1 += v1.y; a2 += v1.z; a3 += v1.w;
      a0 += v2.x; a1 += v2.y; a2 += v2.z; a3 += v2.w;
      a0 += v3.x; a1 += v3.y; a2 += v3.z; a3 += v3.w;
    }
    for (; j < je; ++j){
      int r = srow[s + j];
      float4 v = xp[(size_t)r*2 + h];
      a0 += v.x; a1 += v.y; a2 += v.z; a3 += v.w;
    }
  }
  // exchange halves within the pair
  double e0 = __shfl_xor(a0, 1), e1 = __shfl_xor(a1, 1),
         e2 = __shfl_xor(a2, 1), e3 = __shfl_xor(a3, 1);
  double X[8];
  if (h == 0){ X[0]=a0; X[1]=a1; X[2]=a2; X[3]=a3; X[4]=e0; X[5]=e1; X[6]=e2; X[7]=e3; }
  else       { X[0]=e0; X[1]=e1; X[2]=e2; X[3]=e3; X[4]=a0; X[5]=a1; X[6]=a2; X[7]=a3; }

  double di = dis[i];
  double h2p = 0.0;
  #pragma unroll
  for (int jj = 0; jj < 8; jj++){
    int j = h * 8 + jj;
    double t = 0.0;
    #pragma unroll
    for (int cc = 0; cc < 8; cc++) t += X[cc] * (double)sW0[cc*16 + j];
    t = di * t + (double)sb0[j];
    double x2 = t > 0.0 ? t : 0.0;                 // relu
    h2p += x2 * (double)sW2[j];
  }
  double h2 = h2p + __shfl_xor(h2p, 1);
  if (h == 0) h2s[i] = (float)(di * h2);
}

// ---- layer 2: pair-split neighbor sum ------------------------------------

__global__ void k_agg2(const float* __restrict__ h2s, const int* __restrict__ srow,
                       const int* __restrict__ off, const int* __restrict__ cnt,
                       const double* __restrict__ dis, const float* __restrict__ b2,
                       float* __restrict__ out)
{
  int gid = blockIdx.x * 256 + threadIdx.x;
  int i = gid >> 1, h = gid & 1;
  if (i >= NN) return;
  double acc = (h == 0) ? (double)h2s[i] : 0.0;    // self-loop on lane 0
  int s = off[i], c = cnt[i];
  for (int j = h; j < c; j += 2)
    acc += (double)h2s[srow[s + j]];
  acc += __shfl_xor(acc, 1);
  if (h == 0) out[i] = (float)(dis[i] * acc + (double)b2[0]);
}

// ---- launch --------------------------------------------------------------

extern "C" void kernel_launch(void* const* d_in, const int* in_sizes, int n_in,
                              void* d_out, int out_size, void* d_ws, size_t ws_size,
                              hipStream_t stream)
{
  const int*   edges      = (const int*)  d_in[0];
  const int*   features   = (const int*)  d_in[1];
  const int*   label_mask = (const int*)  d_in[2];
  const float* user_emb   = (const float*)d_in[3];
  const float* known_emb  = (const float*)d_in[4];
  const float* mask_emb   = (const float*)d_in[5];
  const float* cat_emb    = (const float*)d_in[6];
  const float* topic_emb  = (const float*)d_in[7];
  const float* group_emb  = (const float*)d_in[8];
  const float* user_W     = (const float*)d_in[9];
  const float* user_b     = (const float*)d_in[10];
  const float* mask_W     = (const float*)d_in[11];
  const float* mask_b     = (const float*)d_in[12];
  const float* cat_W      = (const float*)d_in[13];
  const float* cat_b      = (const float*)d_in[14];
  const float* topic_W    = (const float*)d_in[15];
  const float* topic_b    = (const float*)d_in[16];
  const float* group_W    = (const float*)d_in[17];
  const float* group_b    = (const float*)d_in[18];
  const float* W0         = (const float*)d_in[19];
  const float* b0         = (const float*)d_in[20];
  const float* W2         = (const float*)d_in[21];
  const float* b2         = (const float*)d_in[22];
  float* out = (float*)d_out;

  char* ws = (char*)d_ws;
  size_t o = 0;
  auto alloc = [&](size_t bytes){ void* p = ws + o; o += (bytes + 255) & ~255ull; return p; };
  int*    binCur = (int*)   alloc((size_t)NBUCK * 4);
  int*    off    = (int*)   alloc((size_t)NN * 4);
  int*    cnt    = (int*)   alloc((size_t)NN * 4);
  int*    seg    = (int*)   alloc((size_t)NN * 4);
  double* dis    = (double*)alloc((size_t)NN * 8);
  int*    srow   = (int*)   alloc((size_t)NBUCK * CAP * 4);   // ~28.8 MB padded
  int*    bin    = (int*)   alloc((size_t)NBUCK * CAP * 4);   // ~28.8 MB padded
  float*  xs1    = (float*) alloc((size_t)NN * 8 * 4);
  float*  h2s    = (float*) alloc((size_t)NN * 4);
  // total ~68 MB of ws (same class as rounds 2-6)

  k_init    <<<(NBUCK + 255)/256, 256, 0, stream>>>(binCur);
  k_binA    <<<NCHUNK, 256, 0, stream>>>(edges, binCur, bin);
  k_binB2   <<<NBUCK,  512, 0, stream>>>(bin, binCur, off, cnt, seg, dis, srow);
  k_assemble<<<NB,     256, 0, stream>>>(features, label_mask,
      user_emb, known_emb, mask_emb, cat_emb, topic_emb, group_emb,
      user_W, user_b, mask_W, mask_b, cat_W, cat_b,
      topic_W, topic_b, group_W, group_b, dis, xs1);
  k_agg1    <<<(2*NN + 255)/256, 256, 0, stream>>>(xs1, srow, off, cnt, seg, dis, b0, W0, W2, h2s);
  k_agg2    <<<(2*NN + 255)/256, 256, 0, stream>>>(h2s, srow, off, cnt, dis, b2, out);
}

// Round 9
// 276.468 us; speedup vs baseline: 1.0042x; 1.0042x over previous
//
#include <hip/hip_runtime.h>
#include <math.h>

constexpr int NN = 200000;
constexpr int EE = 6400000;
constexpr int NB = (NN + 255) / 256;        // 782 blocks of 256 (node-parallel kernels)
constexpr int U_ = 200000, T_ = 20000, C_ = 5000, G_ = 10000;

constexpr int BSH2  = 9;                    // 512 nodes per bucket
constexpr int BUCKN = 1 << BSH2;
constexpr int NBUCK = (NN + BUCKN - 1) / BUCKN;   // 391 (last bucket: 320 nodes)
constexpr int CAP   = 18432;                // padded bucket capacity (mean 16384, ~16 sigma)
constexpr int CHUNK  = 4096;                // edges per chunk
constexpr int NCHUNK = (EE + CHUNK - 1) / CHUNK;  // 1563
constexpr int PER    = (NCHUNK + 255) / 256;      // 7 chunk-counts per scan thread

__device__ __forceinline__ int clampi(int v, int lo, int hi){ return v < lo ? lo : (v > hi ? hi : v); }
__device__ __forceinline__ float reluf(float v){ return v > 0.f ? v : 0.f; }

// ---- Phase 0: per-chunk bucket histogram (coalesced write) ---------------

__global__ void k_hist(const int* __restrict__ edges, int* __restrict__ cntmat){
  __shared__ int h[NBUCK];
  int t = threadIdx.x;
  for (int i = t; i < NBUCK; i += 256) h[i] = 0;
  __syncthreads();
  int base = blockIdx.x * CHUNK;
  int n = min(CHUNK, EE - base);
  for (int k = t; k < n; k += 256)
    atomicAdd(&h[edges[EE + base + k] >> BSH2], 1);
  __syncthreads();
  for (int i = t; i < NBUCK; i += 256)
    cntmat[(size_t)blockIdx.x * NBUCK + i] = h[i];
}

// ---- Phase 1: per-bucket exclusive scan over chunks (no atomics) ---------
// offT[b][chunk] = b*CAP + exclusive_prefix; binCnt[b] = bucket total.

__global__ void k_scan2(const int* __restrict__ cntmat, int* __restrict__ offT,
                        int* __restrict__ binCnt){
  __shared__ int sc[256];
  int t = threadIdx.x;
  int b = blockIdx.x;
  int v[PER];
  int loc = 0;
  #pragma unroll
  for (int j = 0; j < PER; j++){
    int c = t * PER + j;
    v[j] = (c < NCHUNK) ? cntmat[(size_t)c * NBUCK + b] : 0;
    loc += v[j];
  }
  sc[t] = loc; __syncthreads();
  for (int d = 1; d < 256; d <<= 1){
    int u = (t >= d) ? sc[t - d] : 0;
    __syncthreads();
    sc[t] += u;
    __syncthreads();
  }
  int run = b * CAP + sc[t] - loc;           // exclusive prefix + bucket base
  #pragma unroll
  for (int j = 0; j < PER; j++){
    int c = t * PER + j;
    if (c < NCHUNK){ offT[(size_t)b * NCHUNK + c] = run; run += v[j]; }
  }
  if (t == 255) binCnt[b] = sc[255];
}

// ---- Phase 2: direct scatter with precomputed LDS cursors ----------------
// Packed entry: row (bits 0..17, NN < 2^18) | local_col (bits 18..26).

__global__ void k_binA2(const int* __restrict__ edges, const int* __restrict__ offT,
                        int* __restrict__ bin){
  __shared__ int cur[NBUCK];
  int t = threadIdx.x;
  int chunk = blockIdx.x;
  for (int b = t; b < NBUCK; b += 256)
    cur[b] = offT[(size_t)b * NCHUNK + chunk];
  __syncthreads();
  int base = chunk * CHUNK;
  int n = min(CHUNK, EE - base);
  for (int k = t; k < n; k += 256){
    int c = edges[EE + base + k];
    int r = edges[base + k];
    int b = c >> BSH2;
    int p = atomicAdd(&cur[b], 1);
    if (p < (b + 1) * CAP)                   // overflow guard (16-sigma margin)
      bin[p] = r | ((c & (BUCKN - 1)) << 18);
  }
}

// ---- Phase B: per-bucket CSR finalize, sorted by (local_col, row_quarter) -
// Emits off/deg/seg/dis densely; srow within the bucket's contiguous extent.
// seg packs the 3 interior quarter boundaries (10 bits each).

__global__ __launch_bounds__(512) void k_binB2(
    const int* __restrict__ bin, const int* __restrict__ binCnt,
    int* __restrict__ off, int* __restrict__ deg, int* __restrict__ seg,
    double* __restrict__ dis, int* __restrict__ srow){
  __shared__ int hist[4 * BUCKN];   // 2048 keys: (lc<<2)|rq  -> reused as cursors
  __shared__ int sc[512];
  int t = threadIdx.x;
  int b = blockIdx.x;
  int nb = b << BSH2;
  int nloc = min(BUCKN, NN - nb);
  int s0 = b * CAP;
  int s1 = s0 + min(binCnt[b], CAP);

  hist[t] = 0; hist[t + 512] = 0; hist[t + 1024] = 0; hist[t + 1536] = 0;
  __syncthreads();
  for (int k = s0 + t; k < s1; k += 512){
    int w = bin[k];
    int key = ((w >> 18) << 2) | ((w & 0x3FFFF) >> 16);   // rq = row>>16 in 0..3
    atomicAdd(&hist[key], 1);
  }
  __syncthreads();
  int h0 = hist[4*t], h1 = hist[4*t+1], h2 = hist[4*t+2], h3 = hist[4*t+3];
  int tot = h0 + h1 + h2 + h3;
  sc[t] = tot; __syncthreads();
  for (int d = 1; d < 512; d <<= 1){
    int u = (t >= d) ? sc[t - d] : 0;
    __syncthreads();
    sc[t] += u;
    __syncthreads();
  }
  int base = sc[t] - tot;                    // exclusive prefix within bucket
  if (t < nloc){
    off[nb + t] = s0 + base;
    deg[nb + t] = tot;
    seg[nb + t] = h0 | ((h0 + h1) << 10) | ((h0 + h1 + h2) << 20);
    dis[nb + t] = 1.0 / sqrt((double)(tot + 1));   // deg includes self-loop
  }
  __syncthreads();
  hist[4*t]     = base;                      // per-(lc,rq) cursors
  hist[4*t + 1] = base + h0;
  hist[4*t + 2] = base + h0 + h1;
  hist[4*t + 3] = base + h0 + h1 + h2;
  __syncthreads();
  for (int k = s0 + t; k < s1; k += 512){
    int w = bin[k];
    int key = ((w >> 18) << 2) | ((w & 0x3FFFF) >> 16);
    int p = atomicAdd(&hist[key], 1);
    srow[s0 + p] = w & 0x3FFFF;
  }
}

// ---- feature assembly + dis pre-scale -----------------------------------
// xs1[i][k] = dis[i] * x_i[k]   (8 floats/node; W0 applied AFTER aggregation)

__global__ void k_assemble(
    const int* __restrict__ features, const int* __restrict__ lmask,
    const float* __restrict__ user_emb, const float* __restrict__ known_emb,
    const float* __restrict__ mask_emb, const float* __restrict__ cat_emb,
    const float* __restrict__ topic_emb, const float* __restrict__ group_emb,
    const float* __restrict__ user_W, const float* __restrict__ user_b,
    const float* __restrict__ mask_W, const float* __restrict__ mask_b,
    const float* __restrict__ cat_W, const float* __restrict__ cat_b,
    const float* __restrict__ topic_W, const float* __restrict__ topic_b,
    const float* __restrict__ group_W, const float* __restrict__ group_b,
    const double* __restrict__ dis, float* __restrict__ xs1)
{
  __shared__ float s_userW[64], s_topicW[64], s_groupW[64], s_maskW[64];
  __shared__ float s_catW[16], s_knownE[16], s_maskE[16];
  __shared__ float s_userb[8], s_topicb[8], s_catb[8], s_groupb[8], s_maskb[8];
  int tid = threadIdx.x;
  if (tid < 64){ s_userW[tid]=user_W[tid]; s_topicW[tid]=topic_W[tid];
                 s_groupW[tid]=group_W[tid]; s_maskW[tid]=mask_W[tid]; }
  if (tid < 16){ s_catW[tid]=cat_W[tid]; s_knownE[tid]=known_emb[tid]; s_maskE[tid]=mask_emb[tid]; }
  if (tid < 8){ s_userb[tid]=user_b[tid]; s_topicb[tid]=topic_b[tid]; s_catb[tid]=cat_b[tid];
                s_groupb[tid]=group_b[tid]; s_maskb[tid]=mask_b[tid]; }
  __syncthreads();

  int i = blockIdx.x * 256 + tid;
  if (i >= NN) return;

  int idx   = features[3*i + 0];
  int known = features[3*i + 1];
  int tc    = features[3*i + 2];

  double x[8];
  #pragma unroll
  for (int k = 0; k < 8; k++) x[k] = 0.0;

  if (tc == 0){
    int id = clampi(idx, 0, U_-1);
    int kn = clampi(known, 0, 1);
    float a[8];
    #pragma unroll
    for (int d = 0; d < 8; d++) a[d] = reluf(user_emb[(size_t)id*8 + d] + s_knownE[kn*8 + d]);
    #pragma unroll
    for (int k = 0; k < 8; k++){
      double s = (double)s_userb[k];
      #pragma unroll
      for (int d = 0; d < 8; d++) s += (double)a[d] * (double)s_userW[d*8 + k];
      x[k] = s;
    }
  } else if (tc == 1){
    int id = clampi(idx, 0, T_-1);
    float a[8];
    #pragma unroll
    for (int d = 0; d < 8; d++) a[d] = reluf(topic_emb[(size_t)id*8 + d]);
    #pragma unroll
    for (int k = 0; k < 8; k++){
      double s = (double)s_topicb[k];
      #pragma unroll
      for (int d = 0; d < 8; d++) s += (double)a[d] * (double)s_topicW[d*8 + k];
      x[k] = s;
    }
  } else if (tc == 2){
    int id = clampi(idx, 0, C_-1);
    float a0 = reluf(cat_emb[(size_t)id*2 + 0]);
    float a1 = reluf(cat_emb[(size_t)id*2 + 1]);
    #pragma unroll
    for (int k = 0; k < 8; k++)
      x[k] = (double)s_catb[k] + (double)a0*(double)s_catW[k] + (double)a1*(double)s_catW[8 + k];
  } else if (tc == 4){
    int id = clampi(idx, 0, G_-1);
    float a[8];
    #pragma unroll
    for (int d = 0; d < 8; d++) a[d] = reluf(group_emb[(size_t)id*8 + d]);
    #pragma unroll
    for (int k = 0; k < 8; k++){
      double s = (double)s_groupb[k];
      #pragma unroll
      for (int d = 0; d < 8; d++) s += (double)a[d] * (double)s_groupW[d*8 + k];
      x[k] = s;
    }
  } // else: x stays 0 (tcode 3 unused)

  int m = clampi(lmask[i], 0, 1);
  float me[8];
  #pragma unroll
  for (int d = 0; d < 8; d++) me[d] = reluf(s_maskE[m*8 + d]);
  double di = dis[i];
  float xo[8];
  #pragma unroll
  for (int k = 0; k < 8; k++){
    double s = (double)s_maskb[k];
    #pragma unroll
    for (int d = 0; d < 8; d++) s += (double)me[d] * (double)s_maskW[d*8 + k];
    double mf = 1.0 / (1.0 + exp(-s));
    xo[k] = (float)(di * x[k] * mf);
  }
  float4* xp = (float4*)(xs1 + (size_t)i * 8);
  xp[0] = make_float4(xo[0], xo[1], xo[2], xo[3]);
  xp[1] = make_float4(xo[4], xo[5], xo[6], xo[7]);
}

// ---- layer 1: phased gather-aggregate, then W0 + relu + W2 dot -----------
// 2 lanes per node (lane h owns comps h*4..h*4+3). Neighbor lists are sorted
// by row-quarter; all co-resident blocks walk quarters in the same order so
// the instantaneous gather working set (~2.1 MB) stays L2-resident.

__global__ void k_agg1(const float* __restrict__ xs1, const int* __restrict__ srow,
                       const int* __restrict__ off, const int* __restrict__ cnt,
                       const int* __restrict__ seg, const double* __restrict__ dis,
                       const float* __restrict__ b0, const float* __restrict__ W0,
                       const float* __restrict__ W2, float* __restrict__ h2s)
{
  __shared__ float sW0[128], sb0[16], sW2[16];
  int tid = threadIdx.x;
  if (tid < 128) sW0[tid] = W0[tid];
  if (tid < 16){ sb0[tid] = b0[tid]; sW2[tid] = W2[tid]; }
  __syncthreads();

  int gid = blockIdx.x * 256 + tid;
  int i = gid >> 1, h = gid & 1;
  if (i >= NN) return;

  const float4* xp = (const float4*)xs1;
  float4 sv = xp[(size_t)i*2 + h];                 // self-loop
  double a0 = sv.x, a1 = sv.y, a2 = sv.z, a3 = sv.w;
  int s = off[i], c = cnt[i], sg = seg[i];
  int bnd[5];
  bnd[0] = 0;
  bnd[1] = sg & 1023;
  bnd[2] = (sg >> 10) & 1023;
  bnd[3] = (sg >> 20) & 1023;
  bnd[4] = c;
  #pragma unroll 1
  for (int p = 0; p < 4; p++){
    int j = bnd[p], je = bnd[p + 1];
    for (; j + 4 <= je; j += 4){                   // 4 gathers in flight
      int r0 = srow[s+j], r1 = srow[s+j+1], r2 = srow[s+j+2], r3 = srow[s+j+3];
      float4 v0 = xp[(size_t)r0*2 + h], v1 = xp[(size_t)r1*2 + h],
             v2 = xp[(size_t)r2*2 + h], v3 = xp[(size_t)r3*2 + h];
      a0 += v0.x; a1 += v0.y; a2 += v0.z; a3 += v0.w;
      a0 += v1.x; a1 += v1.y; a2 += v1.z; a3 += v1.w;
      a0 += v2.x; a1 += v2.y; a2 += v2.z; a3 += v2.w;
      a0 += v3.x; a1 += v3.y; a2 += v3.z; a3 += v3.w;
    }
    for (; j < je; ++j){
      int r = srow[s + j];
      float4 v = xp[(size_t)r*2 + h];
      a0 += v.x; a1 += v.y; a2 += v.z; a3 += v.w;
    }
  }
  // exchange halves within the pair
  double e0 = __shfl_xor(a0, 1), e1 = __shfl_xor(a1, 1),
         e2 = __shfl_xor(a2, 1), e3 = __shfl_xor(a3, 1);
  double X[8];
  if (h == 0){ X[0]=a0; X[1]=a1; X[2]=a2; X[3]=a3; X[4]=e0; X[5]=e1; X[6]=e2; X[7]=e3; }
  else       { X[0]=e0; X[1]=e1; X[2]=e2; X[3]=e3; X[4]=a0; X[5]=a1; X[6]=a2; X[7]=a3; }

  double di = dis[i];
  double h2p = 0.0;
  #pragma unroll
  for (int jj = 0; jj < 8; jj++){
    int j = h * 8 + jj;
    double t = 0.0;
    #pragma unroll
    for (int cc = 0; cc < 8; cc++) t += X[cc] * (double)sW0[cc*16 + j];
    t = di * t + (double)sb0[j];
    double x2 = t > 0.0 ? t : 0.0;                 // relu
    h2p += x2 * (double)sW2[j];
  }
  double h2 = h2p + __shfl_xor(h2p, 1);
  if (h == 0) h2s[i] = (float)(di * h2);
}

// ---- layer 2: pair-split neighbor sum ------------------------------------

__global__ void k_agg2(const float* __restrict__ h2s, const int* __restrict__ srow,
                       const int* __restrict__ off, const int* __restrict__ cnt,
                       const double* __restrict__ dis, const float* __restrict__ b2,
                       float* __restrict__ out)
{
  int gid = blockIdx.x * 256 + threadIdx.x;
  int i = gid >> 1, h = gid & 1;
  if (i >= NN) return;
  double acc = (h == 0) ? (double)h2s[i] : 0.0;    // self-loop on lane 0
  int s = off[i], c = cnt[i];
  for (int j = h; j < c; j += 2)
    acc += (double)h2s[srow[s + j]];
  acc += __shfl_xor(acc, 1);
  if (h == 0) out[i] = (float)(dis[i] * acc + (double)b2[0]);
}

// ---- launch --------------------------------------------------------------

extern "C" void kernel_launch(void* const* d_in, const int* in_sizes, int n_in,
                              void* d_out, int out_size, void* d_ws, size_t ws_size,
                              hipStream_t stream)
{
  const int*   edges      = (const int*)  d_in[0];
  const int*   features   = (const int*)  d_in[1];
  const int*   label_mask = (const int*)  d_in[2];
  const float* user_emb   = (const float*)d_in[3];
  const float* known_emb  = (const float*)d_in[4];
  const float* mask_emb   = (const float*)d_in[5];
  const float* cat_emb    = (const float*)d_in[6];
  const float* topic_emb  = (const float*)d_in[7];
  const float* group_emb  = (const float*)d_in[8];
  const float* user_W     = (const float*)d_in[9];
  const float* user_b     = (const float*)d_in[10];
  const float* mask_W     = (const float*)d_in[11];
  const float* mask_b     = (const float*)d_in[12];
  const float* cat_W      = (const float*)d_in[13];
  const float* cat_b      = (const float*)d_in[14];
  const float* topic_W    = (const float*)d_in[15];
  const float* topic_b    = (const float*)d_in[16];
  const float* group_W    = (const float*)d_in[17];
  const float* group_b    = (const float*)d_in[18];
  const float* W0         = (const float*)d_in[19];
  const float* b0         = (const float*)d_in[20];
  const float* W2         = (const float*)d_in[21];
  const float* b2         = (const float*)d_in[22];
  float* out = (float*)d_out;

  char* ws = (char*)d_ws;
  size_t o = 0;
  auto alloc = [&](size_t bytes){ void* p = ws + o; o += (bytes + 255) & ~255ull; return p; };
  int*    cntmat = (int*)   alloc((size_t)NCHUNK * NBUCK * 4);  // 2.44 MB
  int*    offT   = (int*)   alloc((size_t)NBUCK * NCHUNK * 4);  // 2.44 MB
  int*    binCnt = (int*)   alloc((size_t)NBUCK * 4);
  int*    off    = (int*)   alloc((size_t)NN * 4);
  int*    deg    = (int*)   alloc((size_t)NN * 4);
  int*    seg    = (int*)   alloc((size_t)NN * 4);
  double* dis    = (double*)alloc((size_t)NN * 8);
  int*    srow   = (int*)   alloc((size_t)NBUCK * CAP * 4);   // ~28.8 MB padded
  int*    bin    = (int*)   alloc((size_t)NBUCK * CAP * 4);   // ~28.8 MB padded
  float*  xs1    = (float*) alloc((size_t)NN * 8 * 4);
  float*  h2s    = (float*) alloc((size_t)NN * 4);
  // total ~73 MB of ws (same class as rounds 2-8)

  k_hist    <<<NCHUNK, 256, 0, stream>>>(edges, cntmat);
  k_scan2   <<<NBUCK,  256, 0, stream>>>(cntmat, offT, binCnt);
  k_binA2   <<<NCHUNK, 256, 0, stream>>>(edges, offT, bin);
  k_binB2   <<<NBUCK,  512, 0, stream>>>(bin, binCnt, off, deg, seg, dis, srow);
  k_assemble<<<NB,     256, 0, stream>>>(features, label_mask,
      user_emb, known_emb, mask_emb, cat_emb, topic_emb, group_emb,
      user_W, user_b, mask_W, mask_b, cat_W, cat_b,
      topic_W, topic_b, group_W, group_b, dis, xs1);
  k_agg1    <<<(2*NN + 255)/256, 256, 0, stream>>>(xs1, srow, off, deg, seg, dis, b0, W0, W2, h2s);
  k_agg2    <<<(2*NN + 255)/256, 256, 0, stream>>>(h2s, srow, off, deg, dis, b2, out);
}

// Round 11
// 224.072 us; speedup vs baseline: 1.2390x; 1.2338x over previous
//
#include <hip/hip_runtime.h>
#include <math.h>

constexpr int NN = 200000;
constexpr int EE = 6400000;
constexpr int NB = (NN + 255) / 256;        // 782 blocks of 256 (node-parallel kernels)
constexpr int U_ = 200000, T_ = 20000, C_ = 5000, G_ = 10000;

constexpr int BSH2  = 9;                    // 512 nodes per bucket
constexpr int BUCKN = 1 << BSH2;
constexpr int NBUCK = (NN + BUCKN - 1) / BUCKN;   // 391 (last bucket: 320 nodes)
constexpr int CAP   = 18432;                // padded bucket capacity (mean 16384, ~16 sigma)
constexpr int CHUNK  = 8192;                // edges per chunk (51KB LDS -> 3 blocks/CU, runs ~21)
constexpr int NCHUNK = (EE + CHUNK - 1) / CHUNK;  // 782
constexpr int PER    = (NCHUNK + 255) / 256;      // 4 chunk-counts per scan thread

__device__ __forceinline__ int clampi(int v, int lo, int hi){ return v < lo ? lo : (v > hi ? hi : v); }
__device__ __forceinline__ float reluf(float v){ return v > 0.f ? v : 0.f; }

// ---- Phase 0: per-chunk bucket histogram (coalesced write) ---------------

__global__ __launch_bounds__(512) void k_hist(const int* __restrict__ edges,
                                              int* __restrict__ cntmat){
  __shared__ int h[NBUCK];
  int t = threadIdx.x;
  for (int i = t; i < NBUCK; i += 512) h[i] = 0;
  __syncthreads();
  int base = blockIdx.x * CHUNK;
  int n = min(CHUNK, EE - base);
  for (int k = t; k < n; k += 512)
    atomicAdd(&h[edges[EE + base + k] >> BSH2], 1);
  __syncthreads();
  for (int i = t; i < NBUCK; i += 512)
    cntmat[(size_t)blockIdx.x * NBUCK + i] = h[i];
}

// ---- Phase 1: per-bucket exclusive scan over chunks (no atomics) ---------
// offT[b][chunk] = b*CAP + exclusive_prefix; binCnt[b] = bucket total.

__global__ void k_scan2(const int* __restrict__ cntmat, int* __restrict__ offT,
                        int* __restrict__ binCnt){
  __shared__ int sc[256];
  int t = threadIdx.x;
  int b = blockIdx.x;
  int v[PER];
  int loc = 0;
  #pragma unroll
  for (int j = 0; j < PER; j++){
    int c = t * PER + j;
    v[j] = (c < NCHUNK) ? cntmat[(size_t)c * NBUCK + b] : 0;
    loc += v[j];
  }
  sc[t] = loc; __syncthreads();
  for (int d = 1; d < 256; d <<= 1){
    int u = (t >= d) ? sc[t - d] : 0;
    __syncthreads();
    sc[t] += u;
    __syncthreads();
  }
  int run = b * CAP + sc[t] - loc;           // exclusive prefix + bucket base
  #pragma unroll
  for (int j = 0; j < PER; j++){
    int c = t * PER + j;
    if (c < NCHUNK){ offT[(size_t)b * NCHUNK + c] = run; run += v[j]; }
  }
  if (t == 255) binCnt[b] = sc[255];
}

// ---- Phase 2: LDS-staged scatter with precomputed offsets ----------------
// Packed entry: row (bits 0..17, NN < 2^18) | local_col (bits 18..26).
// Local bucket starts via 2-barrier wave-shuffle scan; coalesced run writes.

__global__ __launch_bounds__(512) void k_binA3(const int* __restrict__ edges,
                                               const int* __restrict__ cntmat,
                                               const int* __restrict__ offT,
                                               int* __restrict__ bin){
  __shared__ int cur[NBUCK];
  __shared__ int dlt[NBUCK];
  __shared__ int wsum[8];
  __shared__ int stage[CHUNK];
  __shared__ unsigned short stageB[CHUNK];

  int t = threadIdx.x;
  int chunk = blockIdx.x;
  // local exclusive prefix of this chunk's bucket counts (wave-shuffle scan)
  int my = (t < NBUCK) ? cntmat[(size_t)chunk * NBUCK + t] : 0;
  int lane = t & 63, wid = t >> 6;
  int incl = my;
  #pragma unroll
  for (int d = 1; d < 64; d <<= 1){
    int u = __shfl_up(incl, d);
    if (lane >= d) incl += u;
  }
  if (lane == 63) wsum[wid] = incl;
  __syncthreads();
  int wpre = 0;
  #pragma unroll
  for (int w = 0; w < 8; w++) wpre += (w < wid) ? wsum[w] : 0;
  int excl = wpre + incl - my;
  if (t < NBUCK){
    cur[t] = excl;                                  // local staging cursor
    dlt[t] = offT[(size_t)t * NCHUNK + chunk] - excl;
  }
  __syncthreads();
  int base = chunk * CHUNK;
  int n = min(CHUNK, EE - base);
  // scatter packed entries + bucket id into LDS staging, grouped by bucket
  for (int k = t; k < n; k += 512){
    int c = edges[EE + base + k];
    int r = edges[base + k];
    int b = c >> BSH2;
    int p = atomicAdd(&cur[b], 1);
    stage[p]  = r | ((c & (BUCKN - 1)) << 18);
    stageB[p] = (unsigned short)b;
  }
  __syncthreads();
  // write runs out; consecutive k -> consecutive global addr within a run
  for (int k = t; k < n; k += 512){
    int b = stageB[k];
    int addr = dlt[b] + k;
    if (addr < (b + 1) * CAP)                       // overflow guard
      bin[addr] = stage[k];
  }
}

// ---- Phase B: per-bucket CSR finalize, sorted by (local_col, row_quarter) -
// Emits off/deg/seg/dis densely; srow within the bucket's contiguous extent.
// seg packs the 3 interior quarter boundaries (10 bits each).

__global__ __launch_bounds__(512) void k_binB2(
    const int* __restrict__ bin, const int* __restrict__ binCnt,
    int* __restrict__ off, int* __restrict__ deg, int* __restrict__ seg,
    double* __restrict__ dis, int* __restrict__ srow){
  __shared__ int hist[4 * BUCKN];   // 2048 keys: (lc<<2)|rq  -> reused as cursors
  __shared__ int sc[512];
  int t = threadIdx.x;
  int b = blockIdx.x;
  int nb = b << BSH2;
  int nloc = min(BUCKN, NN - nb);
  int s0 = b * CAP;
  int s1 = s0 + min(binCnt[b], CAP);

  hist[t] = 0; hist[t + 512] = 0; hist[t + 1024] = 0; hist[t + 1536] = 0;
  __syncthreads();
  for (int k = s0 + t; k < s1; k += 512){
    int w = bin[k];
    int key = ((w >> 18) << 2) | ((w & 0x3FFFF) >> 16);   // rq = row>>16 in 0..3
    atomicAdd(&hist[key], 1);
  }
  __syncthreads();
  int h0 = hist[4*t], h1 = hist[4*t+1], h2 = hist[4*t+2], h3 = hist[4*t+3];
  int tot = h0 + h1 + h2 + h3;
  sc[t] = tot; __syncthreads();
  for (int d = 1; d < 512; d <<= 1){
    int u = (t >= d) ? sc[t - d] : 0;
    __syncthreads();
    sc[t] += u;
    __syncthreads();
  }
  int base = sc[t] - tot;                    // exclusive prefix within bucket
  if (t < nloc){
    off[nb + t] = s0 + base;
    deg[nb + t] = tot;
    seg[nb + t] = h0 | ((h0 + h1) << 10) | ((h0 + h1 + h2) << 20);
    dis[nb + t] = 1.0 / sqrt((double)(tot + 1));   // deg includes self-loop
  }
  __syncthreads();
  hist[4*t]     = base;                      // per-(lc,rq) cursors
  hist[4*t + 1] = base + h0;
  hist[4*t + 2] = base + h0 + h1;
  hist[4*t + 3] = base + h0 + h1 + h2;
  __syncthreads();
  for (int k = s0 + t; k < s1; k += 512){
    int w = bin[k];
    int key = ((w >> 18) << 2) | ((w & 0x3FFFF) >> 16);
    int p = atomicAdd(&hist[key], 1);
    srow[s0 + p] = w & 0x3FFFF;
  }
}

// ---- feature assembly + dis pre-scale -----------------------------------
// xs1[i][k] = dis[i] * x_i[k]   (8 floats/node; W0 applied AFTER aggregation)

__global__ void k_assemble(
    const int* __restrict__ features, const int* __restrict__ lmask,
    const float* __restrict__ user_emb, const float* __restrict__ known_emb,
    const float* __restrict__ mask_emb, const float* __restrict__ cat_emb,
    const float* __restrict__ topic_emb, const float* __restrict__ group_emb,
    const float* __restrict__ user_W, const float* __restrict__ user_b,
    const float* __restrict__ mask_W, const float* __restrict__ mask_b,
    const float* __restrict__ cat_W, const float* __restrict__ cat_b,
    const float* __restrict__ topic_W, const float* __restrict__ topic_b,
    const float* __restrict__ group_W, const float* __restrict__ group_b,
    const double* __restrict__ dis, float* __restrict__ xs1)
{
  __shared__ float s_userW[64], s_topicW[64], s_groupW[64], s_maskW[64];
  __shared__ float s_catW[16], s_knownE[16], s_maskE[16];
  __shared__ float s_userb[8], s_topicb[8], s_catb[8], s_groupb[8], s_maskb[8];
  int tid = threadIdx.x;
  if (tid < 64){ s_userW[tid]=user_W[tid]; s_topicW[tid]=topic_W[tid];
                 s_groupW[tid]=group_W[tid]; s_maskW[tid]=mask_W[tid]; }
  if (tid < 16){ s_catW[tid]=cat_W[tid]; s_knownE[tid]=known_emb[tid]; s_maskE[tid]=mask_emb[tid]; }
  if (tid < 8){ s_userb[tid]=user_b[tid]; s_topicb[tid]=topic_b[tid]; s_catb[tid]=cat_b[tid];
                s_groupb[tid]=group_b[tid]; s_maskb[tid]=mask_b[tid]; }
  __syncthreads();

  int i = blockIdx.x * 256 + tid;
  if (i >= NN) return;

  int idx   = features[3*i + 0];
  int known = features[3*i + 1];
  int tc    = features[3*i + 2];

  double x[8];
  #pragma unroll
  for (int k = 0; k < 8; k++) x[k] = 0.0;

  if (tc == 0){
    int id = clampi(idx, 0, U_-1);
    int kn = clampi(known, 0, 1);
    float a[8];
    #pragma unroll
    for (int d = 0; d < 8; d++) a[d] = reluf(user_emb[(size_t)id*8 + d] + s_knownE[kn*8 + d]);
    #pragma unroll
    for (int k = 0; k < 8; k++){
      double s = (double)s_userb[k];
      #pragma unroll
      for (int d = 0; d < 8; d++) s += (double)a[d] * (double)s_userW[d*8 + k];
      x[k] = s;
    }
  } else if (tc == 1){
    int id = clampi(idx, 0, T_-1);
    float a[8];
    #pragma unroll
    for (int d = 0; d < 8; d++) a[d] = reluf(topic_emb[(size_t)id*8 + d]);
    #pragma unroll
    for (int k = 0; k < 8; k++){
      double s = (double)s_topicb[k];
      #pragma unroll
      for (int d = 0; d < 8; d++) s += (double)a[d] * (double)s_topicW[d*8 + k];
      x[k] = s;
    }
  } else if (tc == 2){
    int id = clampi(idx, 0, C_-1);
    float a0 = reluf(cat_emb[(size_t)id*2 + 0]);
    float a1 = reluf(cat_emb[(size_t)id*2 + 1]);
    #pragma unroll
    for (int k = 0; k < 8; k++)
      x[k] = (double)s_catb[k] + (double)a0*(double)s_catW[k] + (double)a1*(double)s_catW[8 + k];
  } else if (tc == 4){
    int id = clampi(idx, 0, G_-1);
    float a[8];
    #pragma unroll
    for (int d = 0; d < 8; d++) a[d] = reluf(group_emb[(size_t)id*8 + d]);
    #pragma unroll
    for (int k = 0; k < 8; k++){
      double s = (double)s_groupb[k];
      #pragma unroll
      for (int d = 0; d < 8; d++) s += (double)a[d] * (double)s_groupW[d*8 + k];
      x[k] = s;
    }
  } // else: x stays 0 (tcode 3 unused)

  int m = clampi(lmask[i], 0, 1);
  float me[8];
  #pragma unroll
  for (int d = 0; d < 8; d++) me[d] = reluf(s_maskE[m*8 + d]);
  double di = dis[i];
  float xo[8];
  #pragma unroll
  for (int k = 0; k < 8; k++){
    double s = (double)s_maskb[k];
    #pragma unroll
    for (int d = 0; d < 8; d++) s += (double)me[d] * (double)s_maskW[d*8 + k];
    double mf = 1.0 / (1.0 + exp(-s));
    xo[k] = (float)(di * x[k] * mf);
  }
  float4* xp = (float4*)(xs1 + (size_t)i * 8);
  xp[0] = make_float4(xo[0], xo[1], xo[2], xo[3]);
  xp[1] = make_float4(xo[4], xo[5], xo[6], xo[7]);
}

// ---- layer 1: phased gather-aggregate, then W0 + relu + W2 dot -----------
// 2 lanes per node (lane h owns comps h*4..h*4+3). Neighbor lists are sorted
// by row-quarter; all co-resident blocks walk quarters in the same order so
// the instantaneous gather working set (~2.1 MB) stays L2-resident.

__global__ void k_agg1(const float* __restrict__ xs1, const int* __restrict__ srow,
                       const int* __restrict__ off, const int* __restrict__ cnt,
                       const int* __restrict__ seg, const double* __restrict__ dis,
                       const float* __restrict__ b0, const float* __restrict__ W0,
                       const float* __restrict__ W2, float* __restrict__ h2s)
{
  __shared__ float sW0[128], sb0[16], sW2[16];
  int tid = threadIdx.x;
  if (tid < 128) sW0[tid] = W0[tid];
  if (tid < 16){ sb0[tid] = b0[tid]; sW2[tid] = W2[tid]; }
  __syncthreads();

  int gid = blockIdx.x * 256 + tid;
  int i = gid >> 1, h = gid & 1;
  if (i >= NN) return;

  const float4* xp = (const float4*)xs1;
  float4 sv = xp[(size_t)i*2 + h];                 // self-loop
  double a0 = sv.x, a1 = sv.y, a2 = sv.z, a3 = sv.w;
  int s = off[i], c = cnt[i], sg = seg[i];
  int bnd[5];
  bnd[0] = 0;
  bnd[1] = sg & 1023;
  bnd[2] = (sg >> 10) & 1023;
  bnd[3] = (sg >> 20) & 1023;
  bnd[4] = c;
  #pragma unroll 1
  for (int p = 0; p < 4; p++){
    int j = bnd[p], je = bnd[p + 1];
    for (; j + 4 <= je; j += 4){                   // 4 gathers in flight
      int r0 = srow[s+j], r1 = srow[s+j+1], r2 = srow[s+j+2], r3 = srow[s+j+3];
      float4 v0 = xp[(size_t)r0*2 + h], v1 = xp[(size_t)r1*2 + h],
             v2 = xp[(size_t)r2*2 + h], v3 = xp[(size_t)r3*2 + h];
      a0 += v0.x; a1 += v0.y; a2 += v0.z; a3 += v0.w;
      a0 += v1.x; a1 += v1.y; a2 += v1.z; a3 += v1.w;
      a0 += v2.x; a1 += v2.y; a2 += v2.z; a3 += v2.w;
      a0 += v3.x; a1 += v3.y; a2 += v3.z; a3 += v3.w;
    }
    for (; j < je; ++j){
      int r = srow[s + j];
      float4 v = xp[(size_t)r*2 + h];
      a0 += v.x; a1 += v.y; a2 += v.z; a3 += v.w;
    }
  }
  // exchange halves within the pair
  double e0 = __shfl_xor(a0, 1), e1 = __shfl_xor(a1, 1),
         e2 = __shfl_xor(a2, 1), e3 = __shfl_xor(a3, 1);
  double X[8];
  if (h == 0){ X[0]=a0; X[1]=a1; X[2]=a2; X[3]=a3; X[4]=e0; X[5]=e1; X[6]=e2; X[7]=e3; }
  else       { X[0]=e0; X[1]=e1; X[2]=e2; X[3]=e3; X[4]=a0; X[5]=a1; X[6]=a2; X[7]=a3; }

  double di = dis[i];
  double h2p = 0.0;
  #pragma unroll
  for (int jj = 0; jj < 8; jj++){
    int j = h * 8 + jj;
    double t = 0.0;
    #pragma unroll
    for (int cc = 0; cc < 8; cc++) t += X[cc] * (double)sW0[cc*16 + j];
    t = di * t + (double)sb0[j];
    double x2 = t > 0.0 ? t : 0.0;                 // relu
    h2p += x2 * (double)sW2[j];
  }
  double h2 = h2p + __shfl_xor(h2p, 1);
  if (h == 0) h2s[i] = (float)(di * h2);
}

// ---- layer 2: pair-split neighbor sum ------------------------------------

__global__ void k_agg2(const float* __restrict__ h2s, const int* __restrict__ srow,
                       const int* __restrict__ off, const int* __restrict__ cnt,
                       const double* __restrict__ dis, const float* __restrict__ b2,
                       float* __restrict__ out)
{
  int gid = blockIdx.x * 256 + threadIdx.x;
  int i = gid >> 1, h = gid & 1;
  if (i >= NN) return;
  double acc = (h == 0) ? (double)h2s[i] : 0.0;    // self-loop on lane 0
  int s = off[i], c = cnt[i];
  for (int j = h; j < c; j += 2)
    acc += (double)h2s[srow[s + j]];
  acc += __shfl_xor(acc, 1);
  if (h == 0) out[i] = (float)(dis[i] * acc + (double)b2[0]);
}

// ---- launch --------------------------------------------------------------

extern "C" void kernel_launch(void* const* d_in, const int* in_sizes, int n_in,
                              void* d_out, int out_size, void* d_ws, size_t ws_size,
                              hipStream_t stream)
{
  const int*   edges      = (const int*)  d_in[0];
  const int*   features   = (const int*)  d_in[1];
  const int*   label_mask = (const int*)  d_in[2];
  const float* user_emb   = (const float*)d_in[3];
  const float* known_emb  = (const float*)d_in[4];
  const float* mask_emb   = (const float*)d_in[5];
  const float* cat_emb    = (const float*)d_in[6];
  const float* topic_emb  = (const float*)d_in[7];
  const float* group_emb  = (const float*)d_in[8];
  const float* user_W     = (const float*)d_in[9];
  const float* user_b     = (const float*)d_in[10];
  const float* mask_W     = (const float*)d_in[11];
  const float* mask_b     = (const float*)d_in[12];
  const float* cat_W      = (const float*)d_in[13];
  const float* cat_b      = (const float*)d_in[14];
  const float* topic_W    = (const float*)d_in[15];
  const float* topic_b    = (const float*)d_in[16];
  const float* group_W    = (const float*)d_in[17];
  const float* group_b    = (const float*)d_in[18];
  const float* W0         = (const float*)d_in[19];
  const float* b0         = (const float*)d_in[20];
  const float* W2         = (const float*)d_in[21];
  const float* b2         = (const float*)d_in[22];
  float* out = (float*)d_out;

  char* ws = (char*)d_ws;
  size_t o = 0;
  auto alloc = [&](size_t bytes){ void* p = ws + o; o += (bytes + 255) & ~255ull; return p; };
  int*    cntmat = (int*)   alloc((size_t)NCHUNK * NBUCK * 4);  // 1.22 MB
  int*    offT   = (int*)   alloc((size_t)NBUCK * NCHUNK * 4);  // 1.22 MB
  int*    binCnt = (int*)   alloc((size_t)NBUCK * 4);
  int*    off    = (int*)   alloc((size_t)NN * 4);
  int*    deg    = (int*)   alloc((size_t)NN * 4);
  int*    seg    = (int*)   alloc((size_t)NN * 4);
  double* dis    = (double*)alloc((size_t)NN * 8);
  int*    srow   = (int*)   alloc((size_t)NBUCK * CAP * 4);   // ~28.8 MB padded
  int*    bin    = (int*)   alloc((size_t)NBUCK * CAP * 4);   // ~28.8 MB padded
  float*  xs1    = (float*) alloc((size_t)NN * 8 * 4);
  float*  h2s    = (float*) alloc((size_t)NN * 4);
  // total ~70 MB of ws (same class as rounds 2-9)

  k_hist    <<<NCHUNK, 512, 0, stream>>>(edges, cntmat);
  k_scan2   <<<NBUCK,  256, 0, stream>>>(cntmat, offT, binCnt);
  k_binA3   <<<NCHUNK, 512, 0, stream>>>(edges, cntmat, offT, bin);
  k_binB2   <<<NBUCK,  512, 0, stream>>>(bin, binCnt, off, deg, seg, dis, srow);
  k_assemble<<<NB,     256, 0, stream>>>(features, label_mask,
      user_emb, known_emb, mask_emb, cat_emb, topic_emb, group_emb,
      user_W, user_b, mask_W, mask_b, cat_W, cat_b,
      topic_W, topic_b, group_W, group_b, dis, xs1);
  k_agg1    <<<(2*NN + 255)/256, 256, 0, stream>>>(xs1, srow, off, deg, seg, dis, b0, W0, W2, h2s);
  k_agg2    <<<(2*NN + 255)/256, 256, 0, stream>>>(h2s, srow, off, deg, dis, b2, out);
}

// Round 12
// 184.982 us; speedup vs baseline: 1.5008x; 1.2113x over previous
//
#include <hip/hip_runtime.h>
#include <math.h>

constexpr int NN = 200000;
constexpr int EE = 6400000;
constexpr int NB = (NN + 255) / 256;        // 782 blocks of 256 (node-parallel kernels)
constexpr int U_ = 200000, T_ = 20000, C_ = 5000, G_ = 10000;

constexpr int BSH2  = 9;                    // 512 nodes per bucket
constexpr int BUCKN = 1 << BSH2;
constexpr int NBUCK = (NN + BUCKN - 1) / BUCKN;   // 391 (last bucket: 320 nodes)
constexpr int CAP   = 18432;                // padded bucket capacity (mean 16384, ~16 sigma)
constexpr int CHUNK  = 8192;                // edges per chunk (51KB LDS -> 3 blocks/CU)
constexpr int NCHUNK = (EE + CHUNK - 1) / CHUNK;  // 782
constexpr int PER    = (NCHUNK + 255) / 256;      // 4 chunk-counts per scan thread

__device__ __forceinline__ int clampi(int v, int lo, int hi){ return v < lo ? lo : (v > hi ? hi : v); }
__device__ __forceinline__ float reluf(float v){ return v > 0.f ? v : 0.f; }

// ---- Phase 0: per-chunk bucket histogram (coalesced write) ---------------

__global__ __launch_bounds__(512) void k_hist(const int* __restrict__ edges,
                                              int* __restrict__ cntmat){
  __shared__ int h[NBUCK];
  int t = threadIdx.x;
  for (int i = t; i < NBUCK; i += 512) h[i] = 0;
  __syncthreads();
  int base = blockIdx.x * CHUNK;
  int n = min(CHUNK, EE - base);
  for (int k = t; k < n; k += 512)
    atomicAdd(&h[edges[EE + base + k] >> BSH2], 1);
  __syncthreads();
  for (int i = t; i < NBUCK; i += 512)
    cntmat[(size_t)blockIdx.x * NBUCK + i] = h[i];
}

// ---- Phase 1: per-bucket exclusive scan over chunks (no atomics) ---------
// offT[b][chunk] = b*CAP + exclusive_prefix; binCnt[b] = bucket total.

__global__ void k_scan2(const int* __restrict__ cntmat, int* __restrict__ offT,
                        int* __restrict__ binCnt){
  __shared__ int sc[256];
  int t = threadIdx.x;
  int b = blockIdx.x;
  int v[PER];
  int loc = 0;
  #pragma unroll
  for (int j = 0; j < PER; j++){
    int c = t * PER + j;
    v[j] = (c < NCHUNK) ? cntmat[(size_t)c * NBUCK + b] : 0;
    loc += v[j];
  }
  sc[t] = loc; __syncthreads();
  for (int d = 1; d < 256; d <<= 1){
    int u = (t >= d) ? sc[t - d] : 0;
    __syncthreads();
    sc[t] += u;
    __syncthreads();
  }
  int run = b * CAP + sc[t] - loc;           // exclusive prefix + bucket base
  #pragma unroll
  for (int j = 0; j < PER; j++){
    int c = t * PER + j;
    if (c < NCHUNK){ offT[(size_t)b * NCHUNK + c] = run; run += v[j]; }
  }
  if (t == 255) binCnt[b] = sc[255];
}

// ---- Phase 2: LDS-staged scatter with precomputed offsets ----------------
// Packed entry: row (bits 0..17, NN < 2^18) | local_col (bits 18..26).
// Local bucket starts via 2-barrier wave-shuffle scan; coalesced run writes.

__global__ __launch_bounds__(512) void k_binA3(const int* __restrict__ edges,
                                               const int* __restrict__ cntmat,
                                               const int* __restrict__ offT,
                                               int* __restrict__ bin){
  __shared__ int cur[NBUCK];
  __shared__ int dlt[NBUCK];
  __shared__ int wsum[8];
  __shared__ int stage[CHUNK];
  __shared__ unsigned short stageB[CHUNK];

  int t = threadIdx.x;
  int chunk = blockIdx.x;
  // local exclusive prefix of this chunk's bucket counts (wave-shuffle scan)
  int my = (t < NBUCK) ? cntmat[(size_t)chunk * NBUCK + t] : 0;
  int lane = t & 63, wid = t >> 6;
  int incl = my;
  #pragma unroll
  for (int d = 1; d < 64; d <<= 1){
    int u = __shfl_up(incl, d);
    if (lane >= d) incl += u;
  }
  if (lane == 63) wsum[wid] = incl;
  __syncthreads();
  int wpre = 0;
  #pragma unroll
  for (int w = 0; w < 8; w++) wpre += (w < wid) ? wsum[w] : 0;
  int excl = wpre + incl - my;
  if (t < NBUCK){
    cur[t] = excl;                                  // local staging cursor
    dlt[t] = offT[(size_t)t * NCHUNK + chunk] - excl;
  }
  __syncthreads();
  int base = chunk * CHUNK;
  int n = min(CHUNK, EE - base);
  // scatter packed entries + bucket id into LDS staging, grouped by bucket
  for (int k = t; k < n; k += 512){
    int c = edges[EE + base + k];
    int r = edges[base + k];
    int b = c >> BSH2;
    int p = atomicAdd(&cur[b], 1);
    stage[p]  = r | ((c & (BUCKN - 1)) << 18);
    stageB[p] = (unsigned short)b;
  }
  __syncthreads();
  // write runs out; consecutive k -> consecutive global addr within a run
  for (int k = t; k < n; k += 512){
    int b = stageB[k];
    int addr = dlt[b] + k;
    if (addr < (b + 1) * CAP)                       // overflow guard
      bin[addr] = stage[k];
  }
}

// ---- Phase B: per-bucket CSR finalize, sorted by (local_col, row_quarter).
// Key-sorted scatter lands in LDS; srow written as a coalesced linear dump
// (wave-level write coalescing is the ONLY path to dense HBM writes).

__global__ __launch_bounds__(512) void k_binB2(
    const int* __restrict__ bin, const int* __restrict__ binCnt,
    int* __restrict__ off, int* __restrict__ deg, int* __restrict__ seg,
    double* __restrict__ dis, int* __restrict__ srow){
  __shared__ int hist[4 * BUCKN];   // 2048 keys: (lc<<2)|rq  -> reused as cursors
  __shared__ int sc[512];
  __shared__ int stage[CAP];        // 72 KB sorted-bucket staging
  int t = threadIdx.x;
  int b = blockIdx.x;
  int nb = b << BSH2;
  int nloc = min(BUCKN, NN - nb);
  int s0 = b * CAP;
  int cntb = min(binCnt[b], CAP);
  int s1 = s0 + cntb;

  hist[t] = 0; hist[t + 512] = 0; hist[t + 1024] = 0; hist[t + 1536] = 0;
  __syncthreads();
  for (int k = s0 + t; k < s1; k += 512){
    int w = bin[k];
    int key = ((w >> 18) << 2) | ((w & 0x3FFFF) >> 16);   // rq = row>>16 in 0..3
    atomicAdd(&hist[key], 1);
  }
  __syncthreads();
  int h0 = hist[4*t], h1 = hist[4*t+1], h2 = hist[4*t+2], h3 = hist[4*t+3];
  int tot = h0 + h1 + h2 + h3;
  sc[t] = tot; __syncthreads();
  for (int d = 1; d < 512; d <<= 1){
    int u = (t >= d) ? sc[t - d] : 0;
    __syncthreads();
    sc[t] += u;
    __syncthreads();
  }
  int base = sc[t] - tot;                    // exclusive prefix within bucket
  if (t < nloc){
    off[nb + t] = s0 + base;
    deg[nb + t] = tot;
    seg[nb + t] = h0 | ((h0 + h1) << 10) | ((h0 + h1 + h2) << 20);
    dis[nb + t] = 1.0 / sqrt((double)(tot + 1));   // deg includes self-loop
  }
  __syncthreads();
  hist[4*t]     = base;                      // per-(lc,rq) cursors
  hist[4*t + 1] = base + h0;
  hist[4*t + 2] = base + h0 + h1;
  hist[4*t + 3] = base + h0 + h1 + h2;
  __syncthreads();
  for (int k = s0 + t; k < s1; k += 512){
    int w = bin[k];
    int key = ((w >> 18) << 2) | ((w & 0x3FFFF) >> 16);
    int p = atomicAdd(&hist[key], 1);
    stage[p] = w & 0x3FFFF;                  // scatter into LDS (cheap)
  }
  __syncthreads();
  for (int k = t; k < cntb; k += 512)        // coalesced linear dump
    srow[s0 + k] = stage[k];
}

// ---- feature assembly + dis pre-scale -----------------------------------
// xs1[i][k] = dis[i] * x_i[k]   (8 floats/node; W0 applied AFTER aggregation)

__global__ void k_assemble(
    const int* __restrict__ features, const int* __restrict__ lmask,
    const float* __restrict__ user_emb, const float* __restrict__ known_emb,
    const float* __restrict__ mask_emb, const float* __restrict__ cat_emb,
    const float* __restrict__ topic_emb, const float* __restrict__ group_emb,
    const float* __restrict__ user_W, const float* __restrict__ user_b,
    const float* __restrict__ mask_W, const float* __restrict__ mask_b,
    const float* __restrict__ cat_W, const float* __restrict__ cat_b,
    const float* __restrict__ topic_W, const float* __restrict__ topic_b,
    const float* __restrict__ group_W, const float* __restrict__ group_b,
    const double* __restrict__ dis, float* __restrict__ xs1)
{
  __shared__ float s_userW[64], s_topicW[64], s_groupW[64], s_maskW[64];
  __shared__ float s_catW[16], s_knownE[16], s_maskE[16];
  __shared__ float s_userb[8], s_topicb[8], s_catb[8], s_groupb[8], s_maskb[8];
  int tid = threadIdx.x;
  if (tid < 64){ s_userW[tid]=user_W[tid]; s_topicW[tid]=topic_W[tid];
                 s_groupW[tid]=group_W[tid]; s_maskW[tid]=mask_W[tid]; }
  if (tid < 16){ s_catW[tid]=cat_W[tid]; s_knownE[tid]=known_emb[tid]; s_maskE[tid]=mask_emb[tid]; }
  if (tid < 8){ s_userb[tid]=user_b[tid]; s_topicb[tid]=topic_b[tid]; s_catb[tid]=cat_b[tid];
                s_groupb[tid]=group_b[tid]; s_maskb[tid]=mask_b[tid]; }
  __syncthreads();

  int i = blockIdx.x * 256 + tid;
  if (i >= NN) return;

  int idx   = features[3*i + 0];
  int known = features[3*i + 1];
  int tc    = features[3*i + 2];

  double x[8];
  #pragma unroll
  for (int k = 0; k < 8; k++) x[k] = 0.0;

  if (tc == 0){
    int id = clampi(idx, 0, U_-1);
    int kn = clampi(known, 0, 1);
    float a[8];
    #pragma unroll
    for (int d = 0; d < 8; d++) a[d] = reluf(user_emb[(size_t)id*8 + d] + s_knownE[kn*8 + d]);
    #pragma unroll
    for (int k = 0; k < 8; k++){
      double s = (double)s_userb[k];
      #pragma unroll
      for (int d = 0; d < 8; d++) s += (double)a[d] * (double)s_userW[d*8 + k];
      x[k] = s;
    }
  } else if (tc == 1){
    int id = clampi(idx, 0, T_-1);
    float a[8];
    #pragma unroll
    for (int d = 0; d < 8; d++) a[d] = reluf(topic_emb[(size_t)id*8 + d]);
    #pragma unroll
    for (int k = 0; k < 8; k++){
      double s = (double)s_topicb[k];
      #pragma unroll
      for (int d = 0; d < 8; d++) s += (double)a[d] * (double)s_topicW[d*8 + k];
      x[k] = s;
    }
  } else if (tc == 2){
    int id = clampi(idx, 0, C_-1);
    float a0 = reluf(cat_emb[(size_t)id*2 + 0]);
    float a1 = reluf(cat_emb[(size_t)id*2 + 1]);
    #pragma unroll
    for (int k = 0; k < 8; k++)
      x[k] = (double)s_catb[k] + (double)a0*(double)s_catW[k] + (double)a1*(double)s_catW[8 + k];
  } else if (tc == 4){
    int id = clampi(idx, 0, G_-1);
    float a[8];
    #pragma unroll
    for (int d = 0; d < 8; d++) a[d] = reluf(group_emb[(size_t)id*8 + d]);
    #pragma unroll
    for (int k = 0; k < 8; k++){
      double s = (double)s_groupb[k];
      #pragma unroll
      for (int d = 0; d < 8; d++) s += (double)a[d] * (double)s_groupW[d*8 + k];
      x[k] = s;
    }
  } // else: x stays 0 (tcode 3 unused)

  int m = clampi(lmask[i], 0, 1);
  float me[8];
  #pragma unroll
  for (int d = 0; d < 8; d++) me[d] = reluf(s_maskE[m*8 + d]);
  double di = dis[i];
  float xo[8];
  #pragma unroll
  for (int k = 0; k < 8; k++){
    double s = (double)s_maskb[k];
    #pragma unroll
    for (int d = 0; d < 8; d++) s += (double)me[d] * (double)s_maskW[d*8 + k];
    double mf = 1.0 / (1.0 + exp(-s));
    xo[k] = (float)(di * x[k] * mf);
  }
  float4* xp = (float4*)(xs1 + (size_t)i * 8);
  xp[0] = make_float4(xo[0], xo[1], xo[2], xo[3]);
  xp[1] = make_float4(xo[4], xo[5], xo[6], xo[7]);
}

// ---- layer 1: 4 lanes/node phased gather, then W0 + relu + W2 dot --------
// Lane h in 0..3 owns comps {2h, 2h+1} (float2); 4-lane group reads one
// contiguous 32B xs1 entry per edge. 800K threads saturate the wave cap.

__global__ void k_agg1(const float* __restrict__ xs1, const int* __restrict__ srow,
                       const int* __restrict__ off, const int* __restrict__ cnt,
                       const int* __restrict__ seg, const double* __restrict__ dis,
                       const float* __restrict__ b0, const float* __restrict__ W0,
                       const float* __restrict__ W2, float* __restrict__ h2s)
{
  __shared__ float sW0[128], sb0[16], sW2[16];
  int tid = threadIdx.x;
  if (tid < 128) sW0[tid] = W0[tid];
  if (tid < 16){ sb0[tid] = b0[tid]; sW2[tid] = W2[tid]; }
  __syncthreads();

  int gid = blockIdx.x * 256 + tid;
  int i = gid >> 2, h = gid & 3;
  if (i >= NN) return;

  const float2* xp = (const float2*)xs1;           // 4 float2 per node
  float2 sv = xp[(size_t)i*4 + h];                 // self-loop
  double a0 = sv.x, a1 = sv.y;
  int s = off[i], c = cnt[i], sg = seg[i];
  int bnd[5];
  bnd[0] = 0;
  bnd[1] = sg & 1023;
  bnd[2] = (sg >> 10) & 1023;
  bnd[3] = (sg >> 20) & 1023;
  bnd[4] = c;
  #pragma unroll 1
  for (int p = 0; p < 4; p++){
    int j = bnd[p], je = bnd[p + 1];
    for (; j + 4 <= je; j += 4){                   // 4 gathers in flight
      int r0 = srow[s+j], r1 = srow[s+j+1], r2 = srow[s+j+2], r3 = srow[s+j+3];
      float2 v0 = xp[(size_t)r0*4 + h], v1 = xp[(size_t)r1*4 + h],
             v2 = xp[(size_t)r2*4 + h], v3 = xp[(size_t)r3*4 + h];
      a0 += v0.x; a1 += v0.y;
      a0 += v1.x; a1 += v1.y;
      a0 += v2.x; a1 += v2.y;
      a0 += v3.x; a1 += v3.y;
    }
    for (; j < je; ++j){
      int r = srow[s + j];
      float2 v = xp[(size_t)r*4 + h];
      a0 += v.x; a1 += v.y;
    }
  }
  // butterfly-assemble X[8] across the 4-lane group
  double e0 = __shfl_xor(a0, 1), e1 = __shfl_xor(a1, 1);
  double q0, q1, q2, q3;                           // 4 comps of this half
  if ((h & 1) == 0){ q0 = a0; q1 = a1; q2 = e0; q3 = e1; }
  else             { q0 = e0; q1 = e1; q2 = a0; q3 = a1; }
  double f0 = __shfl_xor(q0, 2), f1 = __shfl_xor(q1, 2),
         f2 = __shfl_xor(q2, 2), f3 = __shfl_xor(q3, 2);
  double X[8];
  if ((h & 2) == 0){ X[0]=q0; X[1]=q1; X[2]=q2; X[3]=q3; X[4]=f0; X[5]=f1; X[6]=f2; X[7]=f3; }
  else             { X[0]=f0; X[1]=f1; X[2]=f2; X[3]=f3; X[4]=q0; X[5]=q1; X[6]=q2; X[7]=q3; }

  double di = dis[i];
  double h2p = 0.0;
  #pragma unroll
  for (int jj = 0; jj < 4; jj++){                  // 4 W0-columns per lane
    int j = h * 4 + jj;
    double t = 0.0;
    #pragma unroll
    for (int cc = 0; cc < 8; cc++) t += X[cc] * (double)sW0[cc*16 + j];
    t = di * t + (double)sb0[j];
    double x2 = t > 0.0 ? t : 0.0;                 // relu
    h2p += x2 * (double)sW2[j];
  }
  h2p += __shfl_xor(h2p, 1);
  h2p += __shfl_xor(h2p, 2);
  if (h == 0) h2s[i] = (float)(di * h2p);
}

// ---- layer 2: 4-lane neighbor sum ----------------------------------------

__global__ void k_agg2(const float* __restrict__ h2s, const int* __restrict__ srow,
                       const int* __restrict__ off, const int* __restrict__ cnt,
                       const double* __restrict__ dis, const float* __restrict__ b2,
                       float* __restrict__ out)
{
  int gid = blockIdx.x * 256 + threadIdx.x;
  int i = gid >> 2, h = gid & 3;
  if (i >= NN) return;
  double acc = (h == 0) ? (double)h2s[i] : 0.0;    // self-loop on lane 0
  int s = off[i], c = cnt[i];
  for (int j = h; j < c; j += 4)
    acc += (double)h2s[srow[s + j]];
  acc += __shfl_xor(acc, 1);
  acc += __shfl_xor(acc, 2);
  if (h == 0) out[i] = (float)(dis[i] * acc + (double)b2[0]);
}

// ---- launch --------------------------------------------------------------

extern "C" void kernel_launch(void* const* d_in, const int* in_sizes, int n_in,
                              void* d_out, int out_size, void* d_ws, size_t ws_size,
                              hipStream_t stream)
{
  const int*   edges      = (const int*)  d_in[0];
  const int*   features   = (const int*)  d_in[1];
  const int*   label_mask = (const int*)  d_in[2];
  const float* user_emb   = (const float*)d_in[3];
  const float* known_emb  = (const float*)d_in[4];
  const float* mask_emb   = (const float*)d_in[5];
  const float* cat_emb    = (const float*)d_in[6];
  const float* topic_emb  = (const float*)d_in[7];
  const float* group_emb  = (const float*)d_in[8];
  const float* user_W     = (const float*)d_in[9];
  const float* user_b     = (const float*)d_in[10];
  const float* mask_W     = (const float*)d_in[11];
  const float* mask_b     = (const float*)d_in[12];
  const float* cat_W      = (const float*)d_in[13];
  const float* cat_b      = (const float*)d_in[14];
  const float* topic_W    = (const float*)d_in[15];
  const float* topic_b    = (const float*)d_in[16];
  const float* group_W    = (const float*)d_in[17];
  const float* group_b    = (const float*)d_in[18];
  const float* W0         = (const float*)d_in[19];
  const float* b0         = (const float*)d_in[20];
  const float* W2         = (const float*)d_in[21];
  const float* b2         = (const float*)d_in[22];
  float* out = (float*)d_out;

  char* ws = (char*)d_ws;
  size_t o = 0;
  auto alloc = [&](size_t bytes){ void* p = ws + o; o += (bytes + 255) & ~255ull; return p; };
  int*    cntmat = (int*)   alloc((size_t)NCHUNK * NBUCK * 4);  // 1.22 MB
  int*    offT   = (int*)   alloc((size_t)NBUCK * NCHUNK * 4);  // 1.22 MB
  int*    binCnt = (int*)   alloc((size_t)NBUCK * 4);
  int*    off    = (int*)   alloc((size_t)NN * 4);
  int*    deg    = (int*)   alloc((size_t)NN * 4);
  int*    seg    = (int*)   alloc((size_t)NN * 4);
  double* dis    = (double*)alloc((size_t)NN * 8);
  int*    srow   = (int*)   alloc((size_t)NBUCK * CAP * 4);   // ~28.8 MB padded
  int*    bin    = (int*)   alloc((size_t)NBUCK * CAP * 4);   // ~28.8 MB padded
  float*  xs1    = (float*) alloc((size_t)NN * 8 * 4);
  float*  h2s    = (float*) alloc((size_t)NN * 4);
  // total ~70 MB of ws (same class as rounds 2-11)

  k_hist    <<<NCHUNK, 512, 0, stream>>>(edges, cntmat);
  k_scan2   <<<NBUCK,  256, 0, stream>>>(cntmat, offT, binCnt);
  k_binA3   <<<NCHUNK, 512, 0, stream>>>(edges, cntmat, offT, bin);
  k_binB2   <<<NBUCK,  512, 0, stream>>>(bin, binCnt, off, deg, seg, dis, srow);
  k_assemble<<<NB,     256, 0, stream>>>(features, label_mask,
      user_emb, known_emb, mask_emb, cat_emb, topic_emb, group_emb,
      user_W, user_b, mask_W, mask_b, cat_W, cat_b,
      topic_W, topic_b, group_W, group_b, dis, xs1);
  k_agg1    <<<(4*NN + 255)/256, 256, 0, stream>>>(xs1, srow, off, deg, seg, dis, b0, W0, W2, h2s);
  k_agg2    <<<(4*NN + 255)/256, 256, 0, stream>>>(h2s, srow, off, deg, dis, b2, out);
}